// Round 8
// baseline (24.284 us; speedup 1.0000x reference)
//
#include <hip/hip_runtime.h>
#include <stdint.h>

// 7x7 stride-2 VALID cross-correlation, X: 4096x4096 fp32, out: 2045x2045 fp32.
// out[i,j] = sum_{p,q} X[2i+p, 2j+q] * W[p,q]
//
// Tile: 32 output rows x 64 cols; grid 512 blocks x 4 horizontally-chained
// tiles. global_load_lds DMA staging (no data VGPRs), double-buffered LDS
// (2 x 40 KiB = 80 KiB -> 2 blocks/CU). T3/T4 pipeline: counted
// s_waitcnt vmcnt(10) + raw s_barrier per tile -- the next tile's DMA stays
// in flight across the barrier (no vmcnt(0) drain in the loop).
// LDS bank-quad swizzle s in {0,1,4,5} on chunks<32: 8 consecutive lanes
// cover all 8 bank quads under P4=36's 4*(lrow&1) quad shift.

static constexpr int H     = 4096;
static constexpr int OUT   = 2045;           // (4096-7)/2 + 1
static constexpr int P4    = 36;             // float4 slots per LDS row
static constexpr int ROWS  = 69;             // tile input-row footprint
static constexpr int SLOTS = ROWS * P4;      // 2484 real slots
static constexpr int NIT   = 10;             // 2560 staged (76 dummies, never read)
static constexpr int ALLOC = NIT * 256;      // 2560 slots = 40 KiB per buffer
static constexpr int NT    = 4;              // tiles chained per block

__device__ __forceinline__ int sel(int q) {  // {0,1,2,3} -> {0,1,4,5}
    return (q & 1) | ((q & 2) << 1);
}
__device__ __forceinline__ int swz(int u, int s) {
    return (u < 32) ? (u ^ s) : u;           // chunks 32..35 (halo) unswizzled
}

__global__ __launch_bounds__(256) void conv7s2_kernel(
    const float* __restrict__ X,
    const float* __restrict__ W,
    float* __restrict__ out)
{
    __shared__ float4 lds4[2][ALLOC];        // 81920 B -> 2 blocks/CU

    const int t = threadIdx.x;
    const int b = blockIdx.x;

    // Uniform-address weight loads -> SGPRs.
    float w[49];
#pragma unroll
    for (int i = 0; i < 49; ++i) w[i] = W[i];

    // Staging decomposition (tile-independent): slot l = t + 256*it ->
    // (lrow, u); slot u of row lrow holds global chunk swz(u, sel((lrow>>2)&3)).
    int lrowA[NIT], G4A[NIT];
#pragma unroll
    for (int it = 0; it < NIT; ++it) {
        const int l  = t + 256 * it;
        const int lr = l / P4;
        const int u  = l - lr * P4;
        lrowA[it] = lr;                       // up to 71 for dummy slots
        G4A[it]   = 4 * swz(u, sel((lr >> 2) & 3));
    }

    // ty-minor lane mapping.
    const int tysub = t & 3;
    const int c     = (t >> 2) & 15;   // col-group: output cols 4c..4c+3
    const int wv    = t >> 6;
    const int rg    = tysub + 4 * wv;  // row-group: output rows 2rg, 2rg+1
    const int c2    = 2 * c;

    auto stage = [&](int buf, int tid) {
        const int C0 = (tid & 31) * 128;
        const int R0 = (tid >> 5) * 64;
#pragma unroll
        for (int it = 0; it < NIT; ++it) {
            const int l = t + 256 * it;       // all lanes active: 10 DMA/wave
            int grow = R0 + lrowA[it];  if (grow > H - 1) grow = H - 1;  // garbage/dummy
            int gcol = C0 + G4A[it];    if (gcol > H - 4) gcol = H - 4;  // guarded outputs
            const float* gp = X + (size_t)grow * H + gcol;
            __builtin_amdgcn_global_load_lds(
                (const __attribute__((address_space(1))) uint32_t*)gp,
                (__attribute__((address_space(3))) uint32_t*)&lds4[buf][l],
                16, 0, 0);
        }
    };

    // Prologue: tile 0 -> buffer 0 (10 outstanding/wave).
    stage(0, 4 * b);

#pragma unroll
    for (int k = 0; k < NT; ++k) {
        const int tid = 4 * b + k;
        const int bx  = tid & 31;
        const int by  = tid >> 5;
        const int cur = k & 1;

        // Issue next tile's DMA first; it streams during this tile's compute.
        if (k + 1 < NT) stage(cur ^ 1, tid + 1);

        // Wait ONLY for tile k's loads (leave the 10 newer ones in flight).
        if (k + 1 < NT) { asm volatile("s_waitcnt vmcnt(10)" ::: "memory"); }
        else           { asm volatile("s_waitcnt vmcnt(0)"  ::: "memory"); }
        __builtin_amdgcn_sched_barrier(0);
        __builtin_amdgcn_s_barrier();          // all waves' tile-k DMA landed
        __builtin_amdgcn_sched_barrier(0);

        float acc0[4] = {0.f, 0.f, 0.f, 0.f};
        float acc1[4] = {0.f, 0.f, 0.f, 0.f};

#pragma unroll
        for (int r = 0; r < 9; ++r) {
            const int lrow = 4 * rg + r;
            const int base = lrow * P4;
            const int s    = sel((rg + (r >> 2)) & 3);   // (4rg+r)>>2 = rg + (r>>2)

            float rv[16];                      // static register indices only
#pragma unroll
            for (int i = 0; i < 4; ++i) {
                const float4 v = lds4[cur][base + swz(c2 + i, s)];
                rv[4 * i + 0] = v.x;
                rv[4 * i + 1] = v.y;
                rv[4 * i + 2] = v.z;
                rv[4 * i + 3] = v.w;
            }

#pragma unroll
            for (int q = 0; q < 7; ++q) {
#pragma unroll
                for (int j = 0; j < 4; ++j) {
                    const float cv = rv[2 * j + q];
                    if (r <= 6) acc0[j] = fmaf(cv, w[r * 7 + q],       acc0[j]);
                    if (r >= 2) acc1[j] = fmaf(cv, w[(r - 2) * 7 + q], acc1[j]);
                }
            }
        }

        const int x0 = bx * 64 + 4 * c;
        const int y0 = by * 32 + 2 * rg;
#pragma unroll
        for (int j = 0; j < 4; ++j) {
            const int x = x0 + j;
            if (x < OUT) {
                if (y0     < OUT) out[(size_t)y0       * OUT + x] = acc0[j];
                if (y0 + 1 < OUT) out[(size_t)(y0 + 1) * OUT + x] = acc1[j];
            }
        }

        // End-of-compute fence: next iteration's stage overwrites buf[cur].
        if (k + 1 < NT) {
            __builtin_amdgcn_sched_barrier(0);
            __builtin_amdgcn_s_barrier();
            __builtin_amdgcn_sched_barrier(0);
        }
    }
}

extern "C" void kernel_launch(void* const* d_in, const int* in_sizes, int n_in,
                              void* d_out, int out_size, void* d_ws, size_t ws_size,
                              hipStream_t stream) {
    const float* X = (const float*)d_in[0];
    const float* W = (const float*)d_in[1];
    float* out = (float*)d_out;

    conv7s2_kernel<<<dim3(512), 256, 0, stream>>>(X, W, out);   // 512 x 4 = 2048 tiles
}